// Round 14
// baseline (135.024 us; speedup 1.0000x reference)
//
#include <hip/hip_runtime.h>
#include <hip/hip_bf16.h>

typedef unsigned short ushortt;

#define BB 4
#define CC 64
#define NN 65536
#define HEADS 8

typedef __attribute__((ext_vector_type(8))) short bf16x8;
typedef __attribute__((ext_vector_type(4))) float f32x4;
typedef __attribute__((ext_vector_type(4))) unsigned int u32x4;

// ---- workspace layout (float offsets) ----
#define OFF_PG   0UL                       // partial gram: 512 slots * 2624
#define OFF_G    1343488UL                 // G: 8 * 4096
#define OFF_S    1376256UL                 // s: 8 * 64
#define OFF_U    1376768UL                 // U = Wq*G: 8 * 4096
#define OFF_V    1409536UL                 // V = Wk*G: 8 * 4096
#define OFF_PS   1442304UL                 // exp partial sums: 4 * 128
#define OFF_CV2  1443328UL                 // cvec halves: 8 * 64
#define OFF_P    1475072UL                 // P (z=0) / Q (z=1): 8 * 4096
#define OFF_L    1508096UL                 // exp(logits): 4 * 65536
// end = 1770240 floats ~= 7.1 MB

__device__ __forceinline__ ushortt f2bf(float f) {
    union { float f; unsigned int i; } v; v.f = f;
    unsigned int x = v.i;
    unsigned int r = x + 0x7FFFu + ((x >> 16) & 1u);
    return (ushortt)(r >> 16);
}

// RNE convert (used only for one-time A-frag loads)
__device__ __forceinline__ bf16x8 ld_cvt(const float* p) {
    const f32x4 a = *(const f32x4*)p;
    const f32x4 b = *(const f32x4*)(p + 4);
    bf16x8 r;
    r[0] = (short)f2bf(a[0]); r[1] = (short)f2bf(a[1]);
    r[2] = (short)f2bf(a[2]); r[3] = (short)f2bf(a[3]);
    r[4] = (short)f2bf(b[0]); r[5] = (short)f2bf(b[1]);
    r[6] = (short)f2bf(b[2]); r[7] = (short)f2bf(b[3]);
    return r;
}

#define PSEL 0x07060302u
// truncation pack: 8 f32 -> 8 bf16 via 4 v_perm_b32 (hi16 extraction)
__device__ __forceinline__ bf16x8 pack_trunc(const f32x4 a, const f32x4 b) {
    union { f32x4 f; u32x4 u; } ua, ub;
    ua.f = a; ub.f = b;
    union { u32x4 u; bf16x8 s; } out;
    out.u[0] = __builtin_amdgcn_perm(ua.u[1], ua.u[0], PSEL);
    out.u[1] = __builtin_amdgcn_perm(ua.u[3], ua.u[2], PSEL);
    out.u[2] = __builtin_amdgcn_perm(ub.u[1], ub.u[0], PSEL);
    out.u[3] = __builtin_amdgcn_perm(ub.u[3], ub.u[2], PSEL);
    return out.s;
}
__device__ __forceinline__ bf16x8 ld_trunc(const float* p) {
    return pack_trunc(*(const f32x4*)p, *(const f32x4*)(p + 4));
}

// branch-free fast tanh: 1 - 2/(exp(2t)+1); exact limits at +-inf.
__device__ __forceinline__ float fast_tanh(float t) {
    const float e = __expf(t + t);
    return 1.f - 2.f * __builtin_amdgcn_rcpf(e + 1.f);
}

#define MFMA(a,b,c) __builtin_amdgcn_mfma_f32_16x16x32_bf16(a,b,c,0,0,0)

// ---------------- K1: Gram pass. G[b,z] = X X^T, s[b,z] = X*1 ------------
__global__ __launch_bounds__(256) void k_gram(const float* __restrict__ x,
                                              const float* __restrict__ y,
                                              float* __restrict__ ws) {
    const int chunk = blockIdx.x;            // 0..63  (1024 px per block)
    const int b = blockIdx.y, z = blockIdx.z;
    const float* X = (z ? y : x) + (size_t)b * CC * NN;
    const int tid = threadIdx.x;
    const int wid = tid >> 6, lane = tid & 63;
    const int lr = lane & 15, lk = lane >> 4;

    f32x4 accG[10];
    f32x4 accS[4];
#pragma unroll
    for (int t = 0; t < 10; ++t) accG[t] = (f32x4){0.f, 0.f, 0.f, 0.f};
#pragma unroll
    for (int g = 0; g < 4; ++g) accS[g] = (f32x4){0.f, 0.f, 0.f, 0.f};
    bf16x8 ones;
#pragma unroll
    for (int j = 0; j < 8; ++j) ones[j] = (short)0x3F80;   // bf16 1.0

    const int p0 = chunk * 1024 + wid * 256;
    for (int ks = 0; ks < 8; ++ks) {
        const int pc = p0 + ks * 32 + lk * 8;
        bf16x8 a0 = ld_trunc(X + (size_t)(0 * 16 + lr) * NN + pc);
        bf16x8 a1 = ld_trunc(X + (size_t)(1 * 16 + lr) * NN + pc);
        bf16x8 a2 = ld_trunc(X + (size_t)(2 * 16 + lr) * NN + pc);
        bf16x8 a3 = ld_trunc(X + (size_t)(3 * 16 + lr) * NN + pc);
        accG[0] = MFMA(a0, a0, accG[0]);
        accG[1] = MFMA(a0, a1, accG[1]);
        accG[2] = MFMA(a0, a2, accG[2]);
        accG[3] = MFMA(a0, a3, accG[3]);
        accG[4] = MFMA(a1, a1, accG[4]);
        accG[5] = MFMA(a1, a2, accG[5]);
        accG[6] = MFMA(a1, a3, accG[6]);
        accG[7] = MFMA(a2, a2, accG[7]);
        accG[8] = MFMA(a2, a3, accG[8]);
        accG[9] = MFMA(a3, a3, accG[9]);
        accS[0] = MFMA(a0, ones, accS[0]);
        accS[1] = MFMA(a1, ones, accS[1]);
        accS[2] = MFMA(a2, ones, accS[2]);
        accS[3] = MFMA(a3, ones, accS[3]);
    }

    // cross-wave reduce in LDS: 10 upper tiles (256 each) + 64 sums
    __shared__ float red[2624];
    for (int i = tid; i < 2624; i += 256) red[i] = 0.f;
    __syncthreads();
    for (int w = 0; w < 4; ++w) {
        if (wid == w) {
#pragma unroll
            for (int ti = 0; ti < 4; ++ti)
#pragma unroll
                for (int tj = ti; tj < 4; ++tj) {
                    const int t = ti * 4 - ti * (ti + 1) / 2 + tj;
#pragma unroll
                    for (int r = 0; r < 4; ++r)
                        red[t * 256 + (lk * 4 + r) * 16 + lr] += accG[t][r];
                }
            if (lr == 0) {
#pragma unroll
                for (int g = 0; g < 4; ++g)
#pragma unroll
                    for (int r = 0; r < 4; ++r)
                        red[2560 + g * 16 + lk * 4 + r] += accS[g][r];
            }
        }
        __syncthreads();
    }
    const int slot = (z * 4 + b) * 64 + chunk;
    float* outp = ws + OFF_PG + (size_t)slot * 2624;
    for (int i = tid; i < 2624; i += 256) outp[i] = red[i];
}

// ---------------- K1b: reduce 64 chunk-partials -> G[8][64][64], s[8][64] --
__global__ void k_reduce(float* __restrict__ ws) {
    const int gid = blockIdx.x * 256 + threadIdx.x;
    if (gid < 8 * 4096) {
        const int zb = gid >> 12;
        const int e = gid & 4095;
        const int row = e >> 6, col = e & 63;
        const int ti = row >> 4, tj = col >> 4;
        int t, elem;
        if (ti <= tj) { t = ti * 4 - ti * (ti + 1) / 2 + tj; elem = (row & 15) * 16 + (col & 15); }
        else          { t = tj * 4 - tj * (tj + 1) / 2 + ti; elem = (col & 15) * 16 + (row & 15); }
        const float* base = ws + OFF_PG + (size_t)(zb * 64) * 2624 + t * 256 + elem;
        float s = 0.f;
        for (int c = 0; c < 64; ++c) s += base[(size_t)c * 2624];
        ws[OFF_G + gid] = s;
    } else if (gid < 8 * 4096 + 8 * 64) {
        const int g2 = gid - 8 * 4096;
        const int zb = g2 >> 6, e = g2 & 63;
        const float* base = ws + OFF_PG + (size_t)(zb * 64) * 2624 + 2560 + e;
        float s = 0.f;
        for (int c = 0; c < 64; ++c) s += base[(size_t)c * 2624];
        ws[OFF_S + g2] = s;
    }
}

// ---------------- K2a: U = Wq*G, V = Wk*G (8 batches*inputs each) ---------
__global__ void k_uv(const float* __restrict__ wq, const float* __restrict__ wk,
                     float* __restrict__ ws) {
    const int gid = blockIdx.x * 256 + threadIdx.x;   // 65536
    const int which = gid >> 15;
    const int rem = gid & 32767;
    const int zb = rem >> 12;
    const int e = rem & 4095;
    const int r = e >> 6, j = e & 63;
    const float* W = which ? wk : wq;
    const float* Gm = ws + OFF_G + (size_t)zb * 4096;
    float acc = 0.f;
    for (int i = 0; i < 64; ++i) acc += W[r * 64 + i] * Gm[i * 64 + j];
    ws[(which ? OFF_V : OFF_U) + (size_t)zb * 4096 + e] = acc;
}

// ---------------- K2b: per-zb attention algebra, all LDS -> P, cv half ---
// 1024 threads (4 waves/SIMD) so the LDS-heavy phases pipeline across waves.
__global__ __launch_bounds__(1024) void k_attn2(
        const float* __restrict__ wq, const float* __restrict__ bq,
        const float* __restrict__ wk, const float* __restrict__ bk,
        const float* __restrict__ wv, const float* __restrict__ bv,
        const float* __restrict__ temp,
        const float* __restrict__ w_ch, const float* __restrict__ b_ch,
        const float* __restrict__ w_y, float* __restrict__ ws) {
    const int zb = blockIdx.x;               // 0..7
    const int z = zb >> 2;
    const int tid = threadIdx.x;             // 0..1023

    __shared__ float Ul[4096], Vl[4096];     // Vl reused as W2 after ph1
    __shared__ float wql[4096], wkl[4096], wvl[4096], wsl[4096];
    __shared__ float sl[64], dq[64], dk[64], wqs[64], wks[64];
    __shared__ float qkl[512], Al[512], cstz[64];
    __shared__ float ph1s[64][16][4];

    // stage everything (coalesced float4, one vector per thread per array)
    {
        const float* Ug = ws + OFF_U + (size_t)zb * 4096;
        const float* Vg = ws + OFF_V + (size_t)zb * 4096;
        const float* wsel = z ? w_y : w_ch;
        const int i = tid * 4;               // 0..4092
        *(f32x4*)(Ul + i)  = *(const f32x4*)(Ug + i);
        *(f32x4*)(Vl + i)  = *(const f32x4*)(Vg + i);
        *(f32x4*)(wql + i) = *(const f32x4*)(wq + i);
        *(f32x4*)(wkl + i) = *(const f32x4*)(wk + i);
        *(f32x4*)(wvl + i) = *(const f32x4*)(wv + i);
        *(f32x4*)(wsl + i) = *(const f32x4*)(wsel + i);
        if (tid < 64) sl[tid] = ws[OFF_S + (size_t)zb * 64 + tid];
    }
    __syncthreads();

    // ph1: norms + weight.s dots (1024-way parallel, LDS reduce)
    {
        const int r = tid >> 4, q = tid & 15;
        float swq = 0.f, swk = 0.f, sqq = 0.f, skk = 0.f;
#pragma unroll
        for (int jj = 0; jj < 4; ++jj) {
            const int j = q * 4 + jj;
            const float svj = sl[j];
            const float wqv = wql[r * 64 + j];
            const float wkv = wkl[r * 64 + j];
            swq += wqv * svj; swk += wkv * svj;
            sqq += Ul[r * 64 + j] * wqv;
            skk += Vl[r * 64 + j] * wkv;
        }
        ph1s[r][q][0] = swq; ph1s[r][q][1] = swk;
        ph1s[r][q][2] = sqq; ph1s[r][q][3] = skk;
    }
    __syncthreads();
    if (tid < 64) {
        const int r = tid;
        float swq = 0.f, swk = 0.f, sqq = 0.f, skk = 0.f;
#pragma unroll
        for (int q = 0; q < 16; ++q) {
            swq += ph1s[r][q][0]; swk += ph1s[r][q][1];
            sqq += ph1s[r][q][2]; skk += ph1s[r][q][3];
        }
        const float bqv = bq[r], bkv = bk[r];
        sqq += 2.f * bqv * swq + 65536.f * bqv * bqv;
        skk += 2.f * bkv * swk + 65536.f * bkv * bkv;
        dq[r] = fmaxf(sqrtf(fmaxf(sqq, 0.f)), 1e-12f);
        dk[r] = fmaxf(sqrtf(fmaxf(skk, 0.f)), 1e-12f);
        wqs[r] = swq; wks[r] = swk;
    }
    __syncthreads();
    // ph2: within-head q.k dots (512 entries, LDS-only inner loop)
    if (tid < 512) {
        const int id = tid;
        const int h = id >> 6, o = (id >> 3) & 7, p = id & 7;
        const int r = h * 8 + o, c = h * 8 + p;
        float acc = 0.f;
#pragma unroll 8
        for (int j = 0; j < 64; ++j) acc += Ul[r * 64 + j] * wkl[c * 64 + j];
        const float bqv = bq[r], bkv = bk[c];
        acc += bqv * wks[c] + bkv * wqs[r] + 65536.f * bqv * bkv;
        qkl[id] = acc;
    }
    __syncthreads();
    // ph3: row softmax -> A, cst half
    if (tid < 64) {
        const int r = tid, h = r >> 3;
        const float tv = temp[h];
        float L[8];
        float m = -1e30f;
#pragma unroll
        for (int p = 0; p < 8; ++p) {
            const float v = qkl[h * 64 + (r & 7) * 8 + p] / (dq[r] * dk[h * 8 + p]) * tv;
            L[p] = v; m = fmaxf(m, v);
        }
        float s = 0.f;
#pragma unroll
        for (int p = 0; p < 8; ++p) { L[p] = __expf(L[p] - m); s += L[p]; }
        const float inv = 1.f / s;
        float cz = bv[r];
#pragma unroll
        for (int p = 0; p < 8; ++p) {
            const float a = L[p] * inv;
            Al[r * 8 + p] = a;
            cz += a * bv[h * 8 + p];
        }
        cstz[r] = cz;
    }
    __syncthreads();
    // ph4: W2 -> Vl (Vl dead after ph1); 4 elements/thread
    for (int o4 = tid; o4 < 4096; o4 += 1024) {
        const int o = o4 >> 6, j = o4 & 63, hj = j >> 3;
        float m = 0.f;
#pragma unroll
        for (int p = 0; p < 8; ++p)
            m += wsl[o * 64 + hj * 8 + p] * Al[(hj * 8 + p) * 8 + (j & 7)];
        Vl[o4] = wsl[o4] + m;
    }
    __syncthreads();
    // ph5: P = W2*Wv + wsel -> global; 4 elements/thread
    for (int o4 = tid; o4 < 4096; o4 += 1024) {
        const int o = o4 >> 6, c = o4 & 63;
        float acc = wsl[o4];
#pragma unroll 8
        for (int j = 0; j < 64; ++j) acc += Vl[o * 64 + j] * wvl[j * 64 + c];
        ws[OFF_P + (size_t)zb * 4096 + o4] = acc;
    }
    // ph6: cv half (z=0 carries b_ch)
    if (tid < 64) {
        const int o = tid;
        float acc = z ? 0.f : b_ch[o];
        for (int r = 0; r < 64; ++r) acc += wsl[o * 64 + r] * cstz[r];
        ws[OFF_CV2 + (size_t)zb * 64 + o] = acc;
    }
}

// ---------------- K3: logits via MFMA, double-buffered LDS staging -------
__global__ __launch_bounds__(256, 2) void k_logits(const float* __restrict__ x,
        const float* __restrict__ y, const float* __restrict__ w_aw,
        const float* __restrict__ b_aw, float* __restrict__ ws) {
    const int b = blockIdx.y;
    const int bx = blockIdx.x;               // 0..127
    const int tid = threadIdx.x;
    const int wid = tid >> 6, lane = tid & 63;
    const int lr = lane & 15, lg = lane >> 4;

    __shared__ float XT[2][64 * 65], YT[2][64 * 65];   // pad 65, double-buffered
    __shared__ float wsum[4];

    const float* Pbase = ws + OFF_P + (size_t)b * 4096;
    const float* Qbase = ws + OFF_P + (size_t)(4 + b) * 4096;

    bf16x8 AP[4][2], AQ[4][2];               // [o-tile][k-step]
#pragma unroll
    for (int ot = 0; ot < 4; ++ot)
#pragma unroll
        for (int ks = 0; ks < 2; ++ks) {
            const int off = (ot * 16 + lr) * 64 + ks * 32 + lg * 8;
            AP[ot][ks] = ld_cvt(Pbase + off);
            AQ[ot][ks] = ld_cvt(Qbase + off);
        }

    float awr[4][4], cvr[4][4];
#pragma unroll
    for (int ot = 0; ot < 4; ++ot)
#pragma unroll
        for (int r = 0; r < 4; ++r) {
            const int o = ot * 16 + lg * 4 + r;
            awr[ot][r] = w_aw[o];
            cvr[ot][r] = ws[OFF_CV2 + b * 64 + o] + ws[OFF_CV2 + (4 + b) * 64 + o];
        }
    const float baw0 = b_aw[0];

    const float* xb = x + (size_t)b * CC * NN;
    const float* yb = y + (size_t)b * CC * NN;
    const int srow = tid >> 2;               // staging: channel row 0..63
    const int scol = (tid & 3) * 16;         // 16-px slice
    const size_t sbase = (size_t)srow * NN + bx * 512 + scol;
    const int ldso = srow * 65 + scol;

    f32x4 rx0, rx1, rx2, rx3, ry0, ry1, ry2, ry3;
    // prologue: load + write chunk 0 into buf 0
    {
        const float* xs = xb + sbase;
        const float* ys = yb + sbase;
        rx0 = *(const f32x4*)xs;       rx1 = *(const f32x4*)(xs + 4);
        rx2 = *(const f32x4*)(xs + 8); rx3 = *(const f32x4*)(xs + 12);
        ry0 = *(const f32x4*)ys;       ry1 = *(const f32x4*)(ys + 4);
        ry2 = *(const f32x4*)(ys + 8); ry3 = *(const f32x4*)(ys + 12);
        float* xd = &XT[0][ldso];
        float* yd = &YT[0][ldso];
#pragma unroll
        for (int i = 0; i < 4; ++i) {
            xd[i] = rx0[i]; xd[4 + i] = rx1[i]; xd[8 + i] = rx2[i]; xd[12 + i] = rx3[i];
            yd[i] = ry0[i]; yd[4 + i] = ry1[i]; yd[8 + i] = ry2[i]; yd[12 + i] = ry3[i];
        }
    }
    __syncthreads();

    float esum = 0.f;
#pragma unroll 1
    for (int ch = 0; ch < 8; ++ch) {
        const int cur = ch & 1;
        // ---- issue next-chunk global loads (latency hides under compute) --
        if (ch < 7) {
            const float* xs = xb + sbase + (ch + 1) * 64;
            const float* ys = yb + sbase + (ch + 1) * 64;
            rx0 = *(const f32x4*)xs;       rx1 = *(const f32x4*)(xs + 4);
            rx2 = *(const f32x4*)(xs + 8); rx3 = *(const f32x4*)(xs + 12);
            ry0 = *(const f32x4*)ys;       ry1 = *(const f32x4*)(ys + 4);
            ry2 = *(const f32x4*)(ys + 8); ry3 = *(const f32x4*)(ys + 12);
        }
        // ---- compute current chunk from LDS buf `cur` ----
        const int p0 = bx * 512 + ch * 64;
        const int pl = wid * 16 + lr;        // local pixel
        const unsigned int* XU = (const unsigned int*)XT[cur];
        const unsigned int* YU = (const unsigned int*)YT[cur];
        bf16x8 BX[2], BY[2];
#pragma unroll
        for (int ks = 0; ks < 2; ++ks) {
            const int c0 = ks * 32 + lg * 8;
            union { u32x4 u; bf16x8 s; } fx, fy;
#pragma unroll
            for (int q = 0; q < 4; ++q) {
                const unsigned int xa = XU[(c0 + 2 * q) * 65 + pl];
                const unsigned int xbv = XU[(c0 + 2 * q + 1) * 65 + pl];
                fx.u[q] = __builtin_amdgcn_perm(xbv, xa, PSEL);
                const unsigned int ya = YU[(c0 + 2 * q) * 65 + pl];
                const unsigned int ybv = YU[(c0 + 2 * q + 1) * 65 + pl];
                fy.u[q] = __builtin_amdgcn_perm(ybv, ya, PSEL);
            }
            BX[ks] = fx.s; BY[ks] = fy.s;
        }
        f32x4 Cf[4];
#pragma unroll
        for (int ot = 0; ot < 4; ++ot) Cf[ot] = (f32x4){0.f, 0.f, 0.f, 0.f};
#pragma unroll
        for (int ot = 0; ot < 4; ++ot)
#pragma unroll
            for (int ks = 0; ks < 2; ++ks) {
                Cf[ot] = MFMA(AP[ot][ks], BX[ks], Cf[ot]);
                Cf[ot] = MFMA(AQ[ot][ks], BY[ks], Cf[ot]);
            }
        float partial = 0.f;
#pragma unroll
        for (int ot = 0; ot < 4; ++ot)
#pragma unroll
            for (int r = 0; r < 4; ++r)
                partial += awr[ot][r] * fast_tanh(Cf[ot][r] + cvr[ot][r]);
        partial += __shfl_xor(partial, 16);
        partial += __shfl_xor(partial, 32);
        const float e = __expf(partial + baw0);   // no-max softmax: |logit| small
        if (lane < 16)
            ws[OFF_L + (size_t)b * NN + p0 + wid * 16 + lane] = e;
        esum += e * 0.25f;                        // 4 identical copies per pixel
        // ---- write next chunk into the other buffer ----
        if (ch < 7) {
            float* xd = &XT[cur ^ 1][ldso];
            float* yd = &YT[cur ^ 1][ldso];
#pragma unroll
            for (int i = 0; i < 4; ++i) {
                xd[i] = rx0[i]; xd[4 + i] = rx1[i]; xd[8 + i] = rx2[i]; xd[12 + i] = rx3[i];
                yd[i] = ry0[i]; yd[4 + i] = ry1[i]; yd[8 + i] = ry2[i]; yd[12 + i] = ry3[i];
            }
        }
        __syncthreads();                          // write(next) -> read(next)
    }
    // block-deterministic partial sum
#pragma unroll
    for (int d = 1; d < 64; d <<= 1) esum += __shfl_xor(esum, d);
    if (lane == 0) wsum[wid] = esum;
    __syncthreads();
    if (tid == 0)
        ws[OFF_PS + (size_t)b * 128 + bx] = wsum[0] + wsum[1] + wsum[2] + wsum[3];
}

// ---------------- K5: out = in * (1 + e/S), nontemporal stores -----------
// 2048 blocks (512 per batch), 4 items/thread; per-block inv computed once.
__global__ __launch_bounds__(256) void k_final(const float* __restrict__ x,
        const float* __restrict__ y, const float* __restrict__ ws,
        float* __restrict__ out) {
    const int bid = blockIdx.x;              // 0..2047
    const int b = bid >> 9;                  // 512 blocks per batch
    const int tid = threadIdx.x;

    __shared__ float invs;
    if (tid < 64) {
        const float* ps = ws + OFF_PS + (size_t)b * 128;
        float s = ps[tid] + ps[64 + tid];
#pragma unroll
        for (int d = 1; d < 64; d <<= 1) s += __shfl_xor(s, d);
        if (tid == 0) invs = 1.f / s;
    }
    __syncthreads();
    const float inv = invs;

    const int ib = (bid & 511) * 1024;       // item base within batch
#pragma unroll
    for (int it = 0; it < 4; ++it) {
        const int item = ib + it * 256 + tid;    // 0..524287
        const int c = item >> 13;
        const int n0 = (item & 8191) * 8;
        const float* w = ws + OFF_L + (size_t)b * NN + n0;
        const f32x4 w0 = *(const f32x4*)w;
        const f32x4 w1 = *(const f32x4*)(w + 4);
        const size_t idx = ((size_t)(b * 64 + c)) * NN + n0;
        const f32x4 x0 = *(const f32x4*)(x + idx);
        const f32x4 x1 = *(const f32x4*)(x + idx + 4);
        const f32x4 y0 = *(const f32x4*)(y + idx);
        const f32x4 y1 = *(const f32x4*)(y + idx + 4);
        f32x4 o0, o1, o2, o3;
#pragma unroll
        for (int j = 0; j < 4; ++j) {
            const float s0 = 1.f + w0[j] * inv;
            const float s1 = 1.f + w1[j] * inv;
            o0[j] = x0[j] * s0;
            o1[j] = x1[j] * s1;
            o2[j] = y0[j] * s0;
            o3[j] = y1[j] * s1;
        }
        __builtin_nontemporal_store(o0, (f32x4*)(out + idx));
        __builtin_nontemporal_store(o1, (f32x4*)(out + idx + 4));
        __builtin_nontemporal_store(o2, (f32x4*)(out + 16777216UL + idx));
        __builtin_nontemporal_store(o3, (f32x4*)(out + 16777216UL + idx + 4));
    }
}

extern "C" void kernel_launch(void* const* d_in, const int* in_sizes, int n_in,
                              void* d_out, int out_size, void* d_ws, size_t ws_size,
                              hipStream_t stream) {
    const float* x    = (const float*)d_in[0];
    const float* y    = (const float*)d_in[1];
    const float* wq   = (const float*)d_in[2];
    const float* bq   = (const float*)d_in[3];
    const float* wk   = (const float*)d_in[4];
    const float* bk   = (const float*)d_in[5];
    const float* wv   = (const float*)d_in[6];
    const float* bv   = (const float*)d_in[7];
    const float* temp = (const float*)d_in[8];
    const float* wch  = (const float*)d_in[9];
    const float* bch  = (const float*)d_in[10];
    const float* wyy  = (const float*)d_in[11];
    const float* waw  = (const float*)d_in[12];
    const float* baw  = (const float*)d_in[13];
    float* out = (float*)d_out;
    float* ws = (float*)d_ws;

    hipLaunchKernelGGL(k_gram, dim3(64, 4, 2), dim3(256), 0, stream, x, y, ws);
    hipLaunchKernelGGL(k_reduce, dim3(130), dim3(256), 0, stream, ws);
    hipLaunchKernelGGL(k_uv, dim3(256), dim3(256), 0, stream, wq, wk, ws);
    hipLaunchKernelGGL(k_attn2, dim3(8), dim3(1024), 0, stream,
                       wq, bq, wk, bk, wv, bv, temp, wch, bch, wyy, ws);
    hipLaunchKernelGGL(k_logits, dim3(128, 4), dim3(256), 0, stream, x, y, waw, baw, ws);
    hipLaunchKernelGGL(k_final, dim3(2048), dim3(256), 0, stream, x, y, ws, out);
}

// Round 15
// 127.260 us; speedup vs baseline: 1.0610x; 1.0610x over previous
//
#include <hip/hip_runtime.h>
#include <hip/hip_bf16.h>

typedef unsigned short ushortt;

#define BB 4
#define CC 64
#define NN 65536
#define HEADS 8

typedef __attribute__((ext_vector_type(8))) short bf16x8;
typedef __attribute__((ext_vector_type(4))) float f32x4;
typedef __attribute__((ext_vector_type(4))) unsigned int u32x4;

// ---- workspace layout (float offsets) ----
#define OFF_PG   0UL                       // partial gram: 512 slots * 2624
#define OFF_G    1343488UL                 // G: 8 * 4096
#define OFF_S    1376256UL                 // s: 8 * 64
#define OFF_PS   1442304UL                 // exp partial sums: 4 * 128
#define OFF_CV2  1443328UL                 // cvec halves: 8 * 64
#define OFF_P    1475072UL                 // P (z=0) / Q (z=1): 8 * 4096
#define OFF_L    1508096UL                 // exp(logits): 4 * 65536
// end = 1770240 floats ~= 7.1 MB

__device__ __forceinline__ ushortt f2bf(float f) {
    union { float f; unsigned int i; } v; v.f = f;
    unsigned int x = v.i;
    unsigned int r = x + 0x7FFFu + ((x >> 16) & 1u);
    return (ushortt)(r >> 16);
}

// RNE convert (used only for one-time A-frag loads)
__device__ __forceinline__ bf16x8 ld_cvt(const float* p) {
    const f32x4 a = *(const f32x4*)p;
    const f32x4 b = *(const f32x4*)(p + 4);
    bf16x8 r;
    r[0] = (short)f2bf(a[0]); r[1] = (short)f2bf(a[1]);
    r[2] = (short)f2bf(a[2]); r[3] = (short)f2bf(a[3]);
    r[4] = (short)f2bf(b[0]); r[5] = (short)f2bf(b[1]);
    r[6] = (short)f2bf(b[2]); r[7] = (short)f2bf(b[3]);
    return r;
}

#define PSEL 0x07060302u
// truncation pack: 8 f32 -> 8 bf16 via 4 v_perm_b32 (hi16 extraction)
__device__ __forceinline__ bf16x8 pack_trunc(const f32x4 a, const f32x4 b) {
    union { f32x4 f; u32x4 u; } ua, ub;
    ua.f = a; ub.f = b;
    union { u32x4 u; bf16x8 s; } out;
    out.u[0] = __builtin_amdgcn_perm(ua.u[1], ua.u[0], PSEL);
    out.u[1] = __builtin_amdgcn_perm(ua.u[3], ua.u[2], PSEL);
    out.u[2] = __builtin_amdgcn_perm(ub.u[1], ub.u[0], PSEL);
    out.u[3] = __builtin_amdgcn_perm(ub.u[3], ub.u[2], PSEL);
    return out.s;
}
__device__ __forceinline__ bf16x8 ld_trunc(const float* p) {
    return pack_trunc(*(const f32x4*)p, *(const f32x4*)(p + 4));
}

// branch-free fast tanh: 1 - 2/(exp(2t)+1); exact limits at +-inf.
__device__ __forceinline__ float fast_tanh(float t) {
    const float e = __expf(t + t);
    return 1.f - 2.f * __builtin_amdgcn_rcpf(e + 1.f);
}

#define MFMA(a,b,c) __builtin_amdgcn_mfma_f32_16x16x32_bf16(a,b,c,0,0,0)

// ---------------- K1: Gram pass. G[b,z] = X X^T, s[b,z] = X*1 ------------
__global__ __launch_bounds__(256) void k_gram(const float* __restrict__ x,
                                              const float* __restrict__ y,
                                              float* __restrict__ ws) {
    const int chunk = blockIdx.x;            // 0..63  (1024 px per block)
    const int b = blockIdx.y, z = blockIdx.z;
    const float* X = (z ? y : x) + (size_t)b * CC * NN;
    const int tid = threadIdx.x;
    const int wid = tid >> 6, lane = tid & 63;
    const int lr = lane & 15, lk = lane >> 4;

    f32x4 accG[10];
    f32x4 accS[4];
#pragma unroll
    for (int t = 0; t < 10; ++t) accG[t] = (f32x4){0.f, 0.f, 0.f, 0.f};
#pragma unroll
    for (int g = 0; g < 4; ++g) accS[g] = (f32x4){0.f, 0.f, 0.f, 0.f};
    bf16x8 ones;
#pragma unroll
    for (int j = 0; j < 8; ++j) ones[j] = (short)0x3F80;   // bf16 1.0

    const int p0 = chunk * 1024 + wid * 256;
    for (int ks = 0; ks < 8; ++ks) {
        const int pc = p0 + ks * 32 + lk * 8;
        bf16x8 a0 = ld_trunc(X + (size_t)(0 * 16 + lr) * NN + pc);
        bf16x8 a1 = ld_trunc(X + (size_t)(1 * 16 + lr) * NN + pc);
        bf16x8 a2 = ld_trunc(X + (size_t)(2 * 16 + lr) * NN + pc);
        bf16x8 a3 = ld_trunc(X + (size_t)(3 * 16 + lr) * NN + pc);
        accG[0] = MFMA(a0, a0, accG[0]);
        accG[1] = MFMA(a0, a1, accG[1]);
        accG[2] = MFMA(a0, a2, accG[2]);
        accG[3] = MFMA(a0, a3, accG[3]);
        accG[4] = MFMA(a1, a1, accG[4]);
        accG[5] = MFMA(a1, a2, accG[5]);
        accG[6] = MFMA(a1, a3, accG[6]);
        accG[7] = MFMA(a2, a2, accG[7]);
        accG[8] = MFMA(a2, a3, accG[8]);
        accG[9] = MFMA(a3, a3, accG[9]);
        accS[0] = MFMA(a0, ones, accS[0]);
        accS[1] = MFMA(a1, ones, accS[1]);
        accS[2] = MFMA(a2, ones, accS[2]);
        accS[3] = MFMA(a3, ones, accS[3]);
    }

    // cross-wave reduce in LDS: 10 upper tiles (256 each) + 64 sums
    __shared__ float red[2624];
    for (int i = tid; i < 2624; i += 256) red[i] = 0.f;
    __syncthreads();
    for (int w = 0; w < 4; ++w) {
        if (wid == w) {
#pragma unroll
            for (int ti = 0; ti < 4; ++ti)
#pragma unroll
                for (int tj = ti; tj < 4; ++tj) {
                    const int t = ti * 4 - ti * (ti + 1) / 2 + tj;
#pragma unroll
                    for (int r = 0; r < 4; ++r)
                        red[t * 256 + (lk * 4 + r) * 16 + lr] += accG[t][r];
                }
            if (lr == 0) {
#pragma unroll
                for (int g = 0; g < 4; ++g)
#pragma unroll
                    for (int r = 0; r < 4; ++r)
                        red[2560 + g * 16 + lk * 4 + r] += accS[g][r];
            }
        }
        __syncthreads();
    }
    const int slot = (z * 4 + b) * 64 + chunk;
    float* outp = ws + OFF_PG + (size_t)slot * 2624;
    for (int i = tid; i < 2624; i += 256) outp[i] = red[i];
}

// ---------------- K1b: reduce 64 chunk-partials -> G[8][64][64], s[8][64] --
__global__ void k_reduce(float* __restrict__ ws) {
    const int gid = blockIdx.x * 256 + threadIdx.x;
    if (gid < 8 * 4096) {
        const int zb = gid >> 12;
        const int e = gid & 4095;
        const int row = e >> 6, col = e & 63;
        const int ti = row >> 4, tj = col >> 4;
        int t, elem;
        if (ti <= tj) { t = ti * 4 - ti * (ti + 1) / 2 + tj; elem = (row & 15) * 16 + (col & 15); }
        else          { t = tj * 4 - tj * (tj + 1) / 2 + ti; elem = (col & 15) * 16 + (row & 15); }
        const float* base = ws + OFF_PG + (size_t)(zb * 64) * 2624 + t * 256 + elem;
        float s = 0.f;
        for (int c = 0; c < 64; ++c) s += base[(size_t)c * 2624];
        ws[OFF_G + gid] = s;
    } else if (gid < 8 * 4096 + 8 * 64) {
        const int g2 = gid - 8 * 4096;
        const int zb = g2 >> 6, e = g2 & 63;
        const float* base = ws + OFF_PG + (size_t)(zb * 64) * 2624 + 2560 + e;
        float s = 0.f;
        for (int c = 0; c < 64; ++c) s += base[(size_t)c * 2624];
        ws[OFF_S + g2] = s;
    }
}

// ---------------- K2: per-zb algebra (G->U,V->attn->P, cv half), 1024 thr -
__global__ __launch_bounds__(1024) void k_attn2(
        const float* __restrict__ wq, const float* __restrict__ bq,
        const float* __restrict__ wk, const float* __restrict__ bk,
        const float* __restrict__ wv, const float* __restrict__ bv,
        const float* __restrict__ temp,
        const float* __restrict__ w_ch, const float* __restrict__ b_ch,
        const float* __restrict__ w_y, float* __restrict__ ws) {
    const int zb = blockIdx.x;               // 0..7
    const int z = zb >> 2;
    const int tid = threadIdx.x;             // 0..1023

    __shared__ float Gl[4096];
    __shared__ float Ul[4096], Vl[4096];     // Vl reused as W2 after ph1
    __shared__ float wql[4096], wkl[4096], wvl[4096], wsl[4096];
    __shared__ float sl[64], dq[64], dk[64], wqs[64], wks[64];
    __shared__ float qkl[512], Al[512], cstz[64];
    __shared__ float ph1s[64][16][4];

    // stage G + all weights (coalesced float4, one vector per thread each)
    {
        const float* Gg = ws + OFF_G + (size_t)zb * 4096;
        const float* wsel = z ? w_y : w_ch;
        const int i = tid * 4;               // 0..4092
        *(f32x4*)(Gl + i)  = *(const f32x4*)(Gg + i);
        *(f32x4*)(wql + i) = *(const f32x4*)(wq + i);
        *(f32x4*)(wkl + i) = *(const f32x4*)(wk + i);
        *(f32x4*)(wvl + i) = *(const f32x4*)(wv + i);
        *(f32x4*)(wsl + i) = *(const f32x4*)(wsel + i);
        if (tid < 64) sl[tid] = ws[OFF_S + (size_t)zb * 64 + tid];
    }
    __syncthreads();

    // ph0: U = Wq*G, V = Wk*G (4 outputs/thread; wql broadcast, Gl j=lane)
    for (int o4 = tid; o4 < 4096; o4 += 1024) {
        const int r = o4 >> 6, j = o4 & 63;
        float au = 0.f, av = 0.f;
#pragma unroll 8
        for (int i = 0; i < 64; ++i) {
            const float g = Gl[i * 64 + j];
            au += wql[r * 64 + i] * g;
            av += wkl[r * 64 + i] * g;
        }
        Ul[o4] = au; Vl[o4] = av;
    }
    __syncthreads();

    // ph1: norms + weight.s dots (1024-way parallel, LDS reduce)
    {
        const int r = tid >> 4, q = tid & 15;
        float swq = 0.f, swk = 0.f, sqq = 0.f, skk = 0.f;
#pragma unroll
        for (int jj = 0; jj < 4; ++jj) {
            const int j = q * 4 + jj;
            const float svj = sl[j];
            const float wqv = wql[r * 64 + j];
            const float wkv = wkl[r * 64 + j];
            swq += wqv * svj; swk += wkv * svj;
            sqq += Ul[r * 64 + j] * wqv;
            skk += Vl[r * 64 + j] * wkv;
        }
        ph1s[r][q][0] = swq; ph1s[r][q][1] = swk;
        ph1s[r][q][2] = sqq; ph1s[r][q][3] = skk;
    }
    __syncthreads();
    if (tid < 64) {
        const int r = tid;
        float swq = 0.f, swk = 0.f, sqq = 0.f, skk = 0.f;
#pragma unroll
        for (int q = 0; q < 16; ++q) {
            swq += ph1s[r][q][0]; swk += ph1s[r][q][1];
            sqq += ph1s[r][q][2]; skk += ph1s[r][q][3];
        }
        const float bqv = bq[r], bkv = bk[r];
        sqq += 2.f * bqv * swq + 65536.f * bqv * bqv;
        skk += 2.f * bkv * swk + 65536.f * bkv * bkv;
        dq[r] = fmaxf(sqrtf(fmaxf(sqq, 0.f)), 1e-12f);
        dk[r] = fmaxf(sqrtf(fmaxf(skk, 0.f)), 1e-12f);
        wqs[r] = swq; wks[r] = swk;
    }
    __syncthreads();
    // ph2: within-head q.k dots (512 entries, LDS-only inner loop)
    if (tid < 512) {
        const int id = tid;
        const int h = id >> 6, o = (id >> 3) & 7, p = id & 7;
        const int r = h * 8 + o, c = h * 8 + p;
        float acc = 0.f;
#pragma unroll 8
        for (int j = 0; j < 64; ++j) acc += Ul[r * 64 + j] * wkl[c * 64 + j];
        const float bqv = bq[r], bkv = bk[c];
        acc += bqv * wks[c] + bkv * wqs[r] + 65536.f * bqv * bkv;
        qkl[id] = acc;
    }
    __syncthreads();
    // ph3: row softmax -> A, cst half
    if (tid < 64) {
        const int r = tid, h = r >> 3;
        const float tv = temp[h];
        float L[8];
        float m = -1e30f;
#pragma unroll
        for (int p = 0; p < 8; ++p) {
            const float v = qkl[h * 64 + (r & 7) * 8 + p] / (dq[r] * dk[h * 8 + p]) * tv;
            L[p] = v; m = fmaxf(m, v);
        }
        float s = 0.f;
#pragma unroll
        for (int p = 0; p < 8; ++p) { L[p] = __expf(L[p] - m); s += L[p]; }
        const float inv = 1.f / s;
        float cz = bv[r];
#pragma unroll
        for (int p = 0; p < 8; ++p) {
            const float a = L[p] * inv;
            Al[r * 8 + p] = a;
            cz += a * bv[h * 8 + p];
        }
        cstz[r] = cz;
    }
    __syncthreads();
    // ph4: W2 -> Vl (Vl dead after ph1); 4 elements/thread
    for (int o4 = tid; o4 < 4096; o4 += 1024) {
        const int o = o4 >> 6, j = o4 & 63, hj = j >> 3;
        float m = 0.f;
#pragma unroll
        for (int p = 0; p < 8; ++p)
            m += wsl[o * 64 + hj * 8 + p] * Al[(hj * 8 + p) * 8 + (j & 7)];
        Vl[o4] = wsl[o4] + m;
    }
    __syncthreads();
    // ph5: P = W2*Wv + wsel -> global; 4 elements/thread
    for (int o4 = tid; o4 < 4096; o4 += 1024) {
        const int o = o4 >> 6, c = o4 & 63;
        float acc = wsl[o4];
#pragma unroll 8
        for (int j = 0; j < 64; ++j) acc += Vl[o * 64 + j] * wvl[j * 64 + c];
        ws[OFF_P + (size_t)zb * 4096 + o4] = acc;
    }
    // ph6: cv half (z=0 carries b_ch)
    if (tid < 64) {
        const int o = tid;
        float acc = z ? 0.f : b_ch[o];
        for (int r = 0; r < 64; ++r) acc += wsl[o * 64 + r] * cstz[r];
        ws[OFF_CV2 + (size_t)zb * 64 + o] = acc;
    }
}

// ---------------- K3: logits via MFMA, double-buffered LDS staging -------
__global__ __launch_bounds__(256, 2) void k_logits(const float* __restrict__ x,
        const float* __restrict__ y, const float* __restrict__ w_aw,
        const float* __restrict__ b_aw, float* __restrict__ ws) {
    const int b = blockIdx.y;
    const int bx = blockIdx.x;               // 0..127
    const int tid = threadIdx.x;
    const int wid = tid >> 6, lane = tid & 63;
    const int lr = lane & 15, lg = lane >> 4;

    __shared__ float XT[2][64 * 65], YT[2][64 * 65];   // pad 65, double-buffered
    __shared__ float wsum[4];

    const float* Pbase = ws + OFF_P + (size_t)b * 4096;
    const float* Qbase = ws + OFF_P + (size_t)(4 + b) * 4096;

    bf16x8 AP[4][2], AQ[4][2];               // [o-tile][k-step]
#pragma unroll
    for (int ot = 0; ot < 4; ++ot)
#pragma unroll
        for (int ks = 0; ks < 2; ++ks) {
            const int off = (ot * 16 + lr) * 64 + ks * 32 + lg * 8;
            AP[ot][ks] = ld_cvt(Pbase + off);
            AQ[ot][ks] = ld_cvt(Qbase + off);
        }

    float awr[4][4], cvr[4][4];
#pragma unroll
    for (int ot = 0; ot < 4; ++ot)
#pragma unroll
        for (int r = 0; r < 4; ++r) {
            const int o = ot * 16 + lg * 4 + r;
            awr[ot][r] = w_aw[o];
            cvr[ot][r] = ws[OFF_CV2 + b * 64 + o] + ws[OFF_CV2 + (4 + b) * 64 + o];
        }
    const float baw0 = b_aw[0];

    const float* xb = x + (size_t)b * CC * NN;
    const float* yb = y + (size_t)b * CC * NN;
    const int srow = tid >> 2;               // staging: channel row 0..63
    const int scol = (tid & 3) * 16;         // 16-px slice
    const size_t sbase = (size_t)srow * NN + bx * 512 + scol;
    const int ldso = srow * 65 + scol;

    f32x4 rx0, rx1, rx2, rx3, ry0, ry1, ry2, ry3;
    // prologue: load + write chunk 0 into buf 0
    {
        const float* xs = xb + sbase;
        const float* ys = yb + sbase;
        rx0 = *(const f32x4*)xs;       rx1 = *(const f32x4*)(xs + 4);
        rx2 = *(const f32x4*)(xs + 8); rx3 = *(const f32x4*)(xs + 12);
        ry0 = *(const f32x4*)ys;       ry1 = *(const f32x4*)(ys + 4);
        ry2 = *(const f32x4*)(ys + 8); ry3 = *(const f32x4*)(ys + 12);
        float* xd = &XT[0][ldso];
        float* yd = &YT[0][ldso];
#pragma unroll
        for (int i = 0; i < 4; ++i) {
            xd[i] = rx0[i]; xd[4 + i] = rx1[i]; xd[8 + i] = rx2[i]; xd[12 + i] = rx3[i];
            yd[i] = ry0[i]; yd[4 + i] = ry1[i]; yd[8 + i] = ry2[i]; yd[12 + i] = ry3[i];
        }
    }
    __syncthreads();

    float esum = 0.f;
#pragma unroll 1
    for (int ch = 0; ch < 8; ++ch) {
        const int cur = ch & 1;
        // ---- issue next-chunk global loads (latency hides under compute) --
        if (ch < 7) {
            const float* xs = xb + sbase + (ch + 1) * 64;
            const float* ys = yb + sbase + (ch + 1) * 64;
            rx0 = *(const f32x4*)xs;       rx1 = *(const f32x4*)(xs + 4);
            rx2 = *(const f32x4*)(xs + 8); rx3 = *(const f32x4*)(xs + 12);
            ry0 = *(const f32x4*)ys;       ry1 = *(const f32x4*)(ys + 4);
            ry2 = *(const f32x4*)(ys + 8); ry3 = *(const f32x4*)(ys + 12);
        }
        // ---- compute current chunk from LDS buf `cur` ----
        const int p0 = bx * 512 + ch * 64;
        const int pl = wid * 16 + lr;        // local pixel
        const unsigned int* XU = (const unsigned int*)XT[cur];
        const unsigned int* YU = (const unsigned int*)YT[cur];
        bf16x8 BX[2], BY[2];
#pragma unroll
        for (int ks = 0; ks < 2; ++ks) {
            const int c0 = ks * 32 + lg * 8;
            union { u32x4 u; bf16x8 s; } fx, fy;
#pragma unroll
            for (int q = 0; q < 4; ++q) {
                const unsigned int xa = XU[(c0 + 2 * q) * 65 + pl];
                const unsigned int xbv = XU[(c0 + 2 * q + 1) * 65 + pl];
                fx.u[q] = __builtin_amdgcn_perm(xbv, xa, PSEL);
                const unsigned int ya = YU[(c0 + 2 * q) * 65 + pl];
                const unsigned int ybv = YU[(c0 + 2 * q + 1) * 65 + pl];
                fy.u[q] = __builtin_amdgcn_perm(ybv, ya, PSEL);
            }
            BX[ks] = fx.s; BY[ks] = fy.s;
        }
        f32x4 Cf[4];
#pragma unroll
        for (int ot = 0; ot < 4; ++ot) Cf[ot] = (f32x4){0.f, 0.f, 0.f, 0.f};
#pragma unroll
        for (int ot = 0; ot < 4; ++ot)
#pragma unroll
            for (int ks = 0; ks < 2; ++ks) {
                Cf[ot] = MFMA(AP[ot][ks], BX[ks], Cf[ot]);
                Cf[ot] = MFMA(AQ[ot][ks], BY[ks], Cf[ot]);
            }
        float partial = 0.f;
#pragma unroll
        for (int ot = 0; ot < 4; ++ot)
#pragma unroll
            for (int r = 0; r < 4; ++r)
                partial += awr[ot][r] * fast_tanh(Cf[ot][r] + cvr[ot][r]);
        partial += __shfl_xor(partial, 16);
        partial += __shfl_xor(partial, 32);
        const float e = __expf(partial + baw0);   // no-max softmax: |logit| small
        if (lane < 16)
            ws[OFF_L + (size_t)b * NN + p0 + wid * 16 + lane] = e;
        esum += e * 0.25f;                        // 4 identical copies per pixel
        // ---- write next chunk into the other buffer ----
        if (ch < 7) {
            float* xd = &XT[cur ^ 1][ldso];
            float* yd = &YT[cur ^ 1][ldso];
#pragma unroll
            for (int i = 0; i < 4; ++i) {
                xd[i] = rx0[i]; xd[4 + i] = rx1[i]; xd[8 + i] = rx2[i]; xd[12 + i] = rx3[i];
                yd[i] = ry0[i]; yd[4 + i] = ry1[i]; yd[8 + i] = ry2[i]; yd[12 + i] = ry3[i];
            }
        }
        __syncthreads();                          // write(next) -> read(next)
    }
    // block-deterministic partial sum
#pragma unroll
    for (int d = 1; d < 64; d <<= 1) esum += __shfl_xor(esum, d);
    if (lane == 0) wsum[wid] = esum;
    __syncthreads();
    if (tid == 0)
        ws[OFF_PS + (size_t)b * 128 + bx] = wsum[0] + wsum[1] + wsum[2] + wsum[3];
}

// ---------------- K5: out = in * (1 + e/S), both outputs (round-13 form) --
__global__ __launch_bounds__(256) void k_final(const float* __restrict__ x,
        const float* __restrict__ y, const float* __restrict__ ws,
        float* __restrict__ out) {
    const int gid = blockIdx.x * 256 + threadIdx.x;   // 2,097,152
    const int b = gid >> 19;
    // deterministic per-batch sum of 128 block partials (identical in every block)
    const int lane = threadIdx.x & 63;
    const float* ps = ws + OFF_PS + (size_t)b * 128;
    float s = ps[lane] + ps[64 + lane];
#pragma unroll
    for (int d = 1; d < 64; d <<= 1) s += __shfl_xor(s, d);
    const float inv = 1.f / s;

    const int rem = gid & 524287;
    const int c = rem >> 13;
    const int n0 = (rem & 8191) * 8;
    const float* w = ws + OFF_L + (size_t)b * NN + n0;
    const f32x4 w0 = *(const f32x4*)w;
    const f32x4 w1 = *(const f32x4*)(w + 4);
    const size_t idx = ((size_t)(b * 64 + c)) * NN + n0;
    const f32x4 x0 = *(const f32x4*)(x + idx);
    const f32x4 x1 = *(const f32x4*)(x + idx + 4);
    const f32x4 y0 = *(const f32x4*)(y + idx);
    const f32x4 y1 = *(const f32x4*)(y + idx + 4);
    f32x4 o0, o1, o2, o3;
#pragma unroll
    for (int j = 0; j < 4; ++j) {
        const float s0 = 1.f + w0[j] * inv;
        const float s1 = 1.f + w1[j] * inv;
        o0[j] = x0[j] * s0;
        o1[j] = x1[j] * s1;
        o2[j] = y0[j] * s0;
        o3[j] = y1[j] * s1;
    }
    *(f32x4*)(out + idx) = o0;
    *(f32x4*)(out + idx + 4) = o1;
    *(f32x4*)(out + 16777216UL + idx) = o2;
    *(f32x4*)(out + 16777216UL + idx + 4) = o3;
}

extern "C" void kernel_launch(void* const* d_in, const int* in_sizes, int n_in,
                              void* d_out, int out_size, void* d_ws, size_t ws_size,
                              hipStream_t stream) {
    const float* x    = (const float*)d_in[0];
    const float* y    = (const float*)d_in[1];
    const float* wq   = (const float*)d_in[2];
    const float* bq   = (const float*)d_in[3];
    const float* wk   = (const float*)d_in[4];
    const float* bk   = (const float*)d_in[5];
    const float* wv   = (const float*)d_in[6];
    const float* bv   = (const float*)d_in[7];
    const float* temp = (const float*)d_in[8];
    const float* wch  = (const float*)d_in[9];
    const float* bch  = (const float*)d_in[10];
    const float* wyy  = (const float*)d_in[11];
    const float* waw  = (const float*)d_in[12];
    const float* baw  = (const float*)d_in[13];
    float* out = (float*)d_out;
    float* ws = (float*)d_ws;

    hipLaunchKernelGGL(k_gram, dim3(64, 4, 2), dim3(256), 0, stream, x, y, ws);
    hipLaunchKernelGGL(k_reduce, dim3(130), dim3(256), 0, stream, ws);
    hipLaunchKernelGGL(k_attn2, dim3(8), dim3(1024), 0, stream,
                       wq, bq, wk, bk, wv, bv, temp, wch, bch, wyy, ws);
    hipLaunchKernelGGL(k_logits, dim3(128, 4), dim3(256), 0, stream, x, y, waw, baw, ws);
    hipLaunchKernelGGL(k_final, dim3(8192), dim3(256), 0, stream, x, y, ws, out);
}

// Round 16
// 123.593 us; speedup vs baseline: 1.0925x; 1.0297x over previous
//
#include <hip/hip_runtime.h>
#include <hip/hip_bf16.h>

typedef unsigned short ushortt;

#define BB 4
#define CC 64
#define NN 65536
#define HEADS 8

typedef __attribute__((ext_vector_type(8))) short bf16x8;
typedef __attribute__((ext_vector_type(4))) float f32x4;
typedef __attribute__((ext_vector_type(4))) unsigned int u32x4;

// ---- workspace layout (float offsets) ----
#define OFF_PG   0UL                       // partial gram: 512 slots * 2624
#define OFF_G    1343488UL                 // G: 8 * 4096
#define OFF_S    1376256UL                 // s: 8 * 64
#define OFF_U    1376768UL                 // U = Wq*G: 8 * 4096
#define OFF_V    1409536UL                 // V = Wk*G: 8 * 4096
#define OFF_PS   1442304UL                 // exp partial sums: 4 * 128
#define OFF_CV2  1443328UL                 // cvec halves: 8 * 64
#define OFF_P    1475072UL                 // P (z=0) / Q (z=1): 8 * 4096
#define OFF_L    1508096UL                 // exp(logits): 4 * 65536
// end = 1770240 floats ~= 7.1 MB

__device__ __forceinline__ ushortt f2bf(float f) {
    union { float f; unsigned int i; } v; v.f = f;
    unsigned int x = v.i;
    unsigned int r = x + 0x7FFFu + ((x >> 16) & 1u);
    return (ushortt)(r >> 16);
}

// RNE convert (used only for one-time A-frag loads)
__device__ __forceinline__ bf16x8 ld_cvt(const float* p) {
    const f32x4 a = *(const f32x4*)p;
    const f32x4 b = *(const f32x4*)(p + 4);
    bf16x8 r;
    r[0] = (short)f2bf(a[0]); r[1] = (short)f2bf(a[1]);
    r[2] = (short)f2bf(a[2]); r[3] = (short)f2bf(a[3]);
    r[4] = (short)f2bf(b[0]); r[5] = (short)f2bf(b[1]);
    r[6] = (short)f2bf(b[2]); r[7] = (short)f2bf(b[3]);
    return r;
}

#define PSEL 0x07060302u
// truncation pack: 8 f32 -> 8 bf16 via 4 v_perm_b32 (hi16 extraction)
__device__ __forceinline__ bf16x8 pack_trunc(const f32x4 a, const f32x4 b) {
    union { f32x4 f; u32x4 u; } ua, ub;
    ua.f = a; ub.f = b;
    union { u32x4 u; bf16x8 s; } out;
    out.u[0] = __builtin_amdgcn_perm(ua.u[1], ua.u[0], PSEL);
    out.u[1] = __builtin_amdgcn_perm(ua.u[3], ua.u[2], PSEL);
    out.u[2] = __builtin_amdgcn_perm(ub.u[1], ub.u[0], PSEL);
    out.u[3] = __builtin_amdgcn_perm(ub.u[3], ub.u[2], PSEL);
    return out.s;
}
__device__ __forceinline__ bf16x8 ld_trunc(const float* p) {
    return pack_trunc(*(const f32x4*)p, *(const f32x4*)(p + 4));
}

// branch-free fast tanh: 1 - 2/(exp(2t)+1); exact limits at +-inf.
__device__ __forceinline__ float fast_tanh(float t) {
    const float e = __expf(t + t);
    return 1.f - 2.f * __builtin_amdgcn_rcpf(e + 1.f);
}

#define MFMA(a,b,c) __builtin_amdgcn_mfma_f32_16x16x32_bf16(a,b,c,0,0,0)

// ---------------- K1: Gram pass. G[b,z] = X X^T, s[b,z] = X*1 ------------
__global__ __launch_bounds__(256) void k_gram(const float* __restrict__ x,
                                              const float* __restrict__ y,
                                              float* __restrict__ ws) {
    const int chunk = blockIdx.x;            // 0..63  (1024 px per block)
    const int b = blockIdx.y, z = blockIdx.z;
    const float* X = (z ? y : x) + (size_t)b * CC * NN;
    const int tid = threadIdx.x;
    const int wid = tid >> 6, lane = tid & 63;
    const int lr = lane & 15, lk = lane >> 4;

    f32x4 accG[10];
    f32x4 accS[4];
#pragma unroll
    for (int t = 0; t < 10; ++t) accG[t] = (f32x4){0.f, 0.f, 0.f, 0.f};
#pragma unroll
    for (int g = 0; g < 4; ++g) accS[g] = (f32x4){0.f, 0.f, 0.f, 0.f};
    bf16x8 ones;
#pragma unroll
    for (int j = 0; j < 8; ++j) ones[j] = (short)0x3F80;   // bf16 1.0

    const int p0 = chunk * 1024 + wid * 256;
    for (int ks = 0; ks < 8; ++ks) {
        const int pc = p0 + ks * 32 + lk * 8;
        bf16x8 a0 = ld_trunc(X + (size_t)(0 * 16 + lr) * NN + pc);
        bf16x8 a1 = ld_trunc(X + (size_t)(1 * 16 + lr) * NN + pc);
        bf16x8 a2 = ld_trunc(X + (size_t)(2 * 16 + lr) * NN + pc);
        bf16x8 a3 = ld_trunc(X + (size_t)(3 * 16 + lr) * NN + pc);
        accG[0] = MFMA(a0, a0, accG[0]);
        accG[1] = MFMA(a0, a1, accG[1]);
        accG[2] = MFMA(a0, a2, accG[2]);
        accG[3] = MFMA(a0, a3, accG[3]);
        accG[4] = MFMA(a1, a1, accG[4]);
        accG[5] = MFMA(a1, a2, accG[5]);
        accG[6] = MFMA(a1, a3, accG[6]);
        accG[7] = MFMA(a2, a2, accG[7]);
        accG[8] = MFMA(a2, a3, accG[8]);
        accG[9] = MFMA(a3, a3, accG[9]);
        accS[0] = MFMA(a0, ones, accS[0]);
        accS[1] = MFMA(a1, ones, accS[1]);
        accS[2] = MFMA(a2, ones, accS[2]);
        accS[3] = MFMA(a3, ones, accS[3]);
    }

    // cross-wave reduce in LDS: 10 upper tiles (256 each) + 64 sums
    __shared__ float red[2624];
    for (int i = tid; i < 2624; i += 256) red[i] = 0.f;
    __syncthreads();
    for (int w = 0; w < 4; ++w) {
        if (wid == w) {
#pragma unroll
            for (int ti = 0; ti < 4; ++ti)
#pragma unroll
                for (int tj = ti; tj < 4; ++tj) {
                    const int t = ti * 4 - ti * (ti + 1) / 2 + tj;
#pragma unroll
                    for (int r = 0; r < 4; ++r)
                        red[t * 256 + (lk * 4 + r) * 16 + lr] += accG[t][r];
                }
            if (lr == 0) {
#pragma unroll
                for (int g = 0; g < 4; ++g)
#pragma unroll
                    for (int r = 0; r < 4; ++r)
                        red[2560 + g * 16 + lk * 4 + r] += accS[g][r];
            }
        }
        __syncthreads();
    }
    const int slot = (z * 4 + b) * 64 + chunk;
    float* outp = ws + OFF_PG + (size_t)slot * 2624;
    for (int i = tid; i < 2624; i += 256) outp[i] = red[i];
}

// ---------------- K1b: reduce 64 chunk-partials -> G[8][64][64], s[8][64] --
__global__ void k_reduce(float* __restrict__ ws) {
    const int gid = blockIdx.x * 256 + threadIdx.x;
    if (gid < 8 * 4096) {
        const int zb = gid >> 12;
        const int e = gid & 4095;
        const int row = e >> 6, col = e & 63;
        const int ti = row >> 4, tj = col >> 4;
        int t, elem;
        if (ti <= tj) { t = ti * 4 - ti * (ti + 1) / 2 + tj; elem = (row & 15) * 16 + (col & 15); }
        else          { t = tj * 4 - tj * (tj + 1) / 2 + ti; elem = (col & 15) * 16 + (row & 15); }
        const float* base = ws + OFF_PG + (size_t)(zb * 64) * 2624 + t * 256 + elem;
        float s = 0.f;
        for (int c = 0; c < 64; ++c) s += base[(size_t)c * 2624];
        ws[OFF_G + gid] = s;
    } else if (gid < 8 * 4096 + 8 * 64) {
        const int g2 = gid - 8 * 4096;
        const int zb = g2 >> 6, e = g2 & 63;
        const float* base = ws + OFF_PG + (size_t)(zb * 64) * 2624 + 2560 + e;
        float s = 0.f;
        for (int c = 0; c < 64; ++c) s += base[(size_t)c * 2624];
        ws[OFF_S + g2] = s;
    }
}

// ---------------- K2a: U = Wq*G, V = Wk*G (8 batches*inputs each) ---------
__global__ void k_uv(const float* __restrict__ wq, const float* __restrict__ wk,
                     float* __restrict__ ws) {
    const int gid = blockIdx.x * 256 + threadIdx.x;   // 65536
    const int which = gid >> 15;
    const int rem = gid & 32767;
    const int zb = rem >> 12;
    const int e = rem & 4095;
    const int r = e >> 6, j = e & 63;
    const float* W = which ? wk : wq;
    const float* Gm = ws + OFF_G + (size_t)zb * 4096;
    float acc = 0.f;
    for (int i = 0; i < 64; ++i) acc += W[r * 64 + i] * Gm[i * 64 + j];
    ws[(which ? OFF_V : OFF_U) + (size_t)zb * 4096 + e] = acc;
}

// ---------------- K2b: per-zb attention algebra, all LDS -> P, cv half ---
// 1024 threads (4 waves/SIMD) so the LDS-heavy phases pipeline across waves.
__global__ __launch_bounds__(1024) void k_attn2(
        const float* __restrict__ wq, const float* __restrict__ bq,
        const float* __restrict__ wk, const float* __restrict__ bk,
        const float* __restrict__ wv, const float* __restrict__ bv,
        const float* __restrict__ temp,
        const float* __restrict__ w_ch, const float* __restrict__ b_ch,
        const float* __restrict__ w_y, float* __restrict__ ws) {
    const int zb = blockIdx.x;               // 0..7
    const int z = zb >> 2;
    const int tid = threadIdx.x;             // 0..1023

    __shared__ float Ul[4096], Vl[4096];     // Vl reused as W2 after ph1
    __shared__ float wql[4096], wkl[4096], wvl[4096], wsl[4096];
    __shared__ float sl[64], dq[64], dk[64], wqs[64], wks[64];
    __shared__ float qkl[512], Al[512], cstz[64];
    __shared__ float ph1s[64][16][4];

    // stage everything (coalesced float4, one vector per thread per array)
    {
        const float* Ug = ws + OFF_U + (size_t)zb * 4096;
        const float* Vg = ws + OFF_V + (size_t)zb * 4096;
        const float* wsel = z ? w_y : w_ch;
        const int i = tid * 4;               // 0..4092
        *(f32x4*)(Ul + i)  = *(const f32x4*)(Ug + i);
        *(f32x4*)(Vl + i)  = *(const f32x4*)(Vg + i);
        *(f32x4*)(wql + i) = *(const f32x4*)(wq + i);
        *(f32x4*)(wkl + i) = *(const f32x4*)(wk + i);
        *(f32x4*)(wvl + i) = *(const f32x4*)(wv + i);
        *(f32x4*)(wsl + i) = *(const f32x4*)(wsel + i);
        if (tid < 64) sl[tid] = ws[OFF_S + (size_t)zb * 64 + tid];
    }
    __syncthreads();

    // ph1: norms + weight.s dots (1024-way parallel, LDS reduce)
    {
        const int r = tid >> 4, q = tid & 15;
        float swq = 0.f, swk = 0.f, sqq = 0.f, skk = 0.f;
#pragma unroll
        for (int jj = 0; jj < 4; ++jj) {
            const int j = q * 4 + jj;
            const float svj = sl[j];
            const float wqv = wql[r * 64 + j];
            const float wkv = wkl[r * 64 + j];
            swq += wqv * svj; swk += wkv * svj;
            sqq += Ul[r * 64 + j] * wqv;
            skk += Vl[r * 64 + j] * wkv;
        }
        ph1s[r][q][0] = swq; ph1s[r][q][1] = swk;
        ph1s[r][q][2] = sqq; ph1s[r][q][3] = skk;
    }
    __syncthreads();
    if (tid < 64) {
        const int r = tid;
        float swq = 0.f, swk = 0.f, sqq = 0.f, skk = 0.f;
#pragma unroll
        for (int q = 0; q < 16; ++q) {
            swq += ph1s[r][q][0]; swk += ph1s[r][q][1];
            sqq += ph1s[r][q][2]; skk += ph1s[r][q][3];
        }
        const float bqv = bq[r], bkv = bk[r];
        sqq += 2.f * bqv * swq + 65536.f * bqv * bqv;
        skk += 2.f * bkv * swk + 65536.f * bkv * bkv;
        dq[r] = fmaxf(sqrtf(fmaxf(sqq, 0.f)), 1e-12f);
        dk[r] = fmaxf(sqrtf(fmaxf(skk, 0.f)), 1e-12f);
        wqs[r] = swq; wks[r] = swk;
    }
    __syncthreads();
    // ph2: within-head q.k dots (512 entries, LDS-only inner loop)
    if (tid < 512) {
        const int id = tid;
        const int h = id >> 6, o = (id >> 3) & 7, p = id & 7;
        const int r = h * 8 + o, c = h * 8 + p;
        float acc = 0.f;
#pragma unroll 8
        for (int j = 0; j < 64; ++j) acc += Ul[r * 64 + j] * wkl[c * 64 + j];
        const float bqv = bq[r], bkv = bk[c];
        acc += bqv * wks[c] + bkv * wqs[r] + 65536.f * bqv * bkv;
        qkl[id] = acc;
    }
    __syncthreads();
    // ph3: row softmax -> A, cst half
    if (tid < 64) {
        const int r = tid, h = r >> 3;
        const float tv = temp[h];
        float L[8];
        float m = -1e30f;
#pragma unroll
        for (int p = 0; p < 8; ++p) {
            const float v = qkl[h * 64 + (r & 7) * 8 + p] / (dq[r] * dk[h * 8 + p]) * tv;
            L[p] = v; m = fmaxf(m, v);
        }
        float s = 0.f;
#pragma unroll
        for (int p = 0; p < 8; ++p) { L[p] = __expf(L[p] - m); s += L[p]; }
        const float inv = 1.f / s;
        float cz = bv[r];
#pragma unroll
        for (int p = 0; p < 8; ++p) {
            const float a = L[p] * inv;
            Al[r * 8 + p] = a;
            cz += a * bv[h * 8 + p];
        }
        cstz[r] = cz;
    }
    __syncthreads();
    // ph4: W2 -> Vl (Vl dead after ph1); 4 elements/thread
    for (int o4 = tid; o4 < 4096; o4 += 1024) {
        const int o = o4 >> 6, j = o4 & 63, hj = j >> 3;
        float m = 0.f;
#pragma unroll
        for (int p = 0; p < 8; ++p)
            m += wsl[o * 64 + hj * 8 + p] * Al[(hj * 8 + p) * 8 + (j & 7)];
        Vl[o4] = wsl[o4] + m;
    }
    __syncthreads();
    // ph5: P = W2*Wv + wsel -> global; 4 elements/thread
    for (int o4 = tid; o4 < 4096; o4 += 1024) {
        const int o = o4 >> 6, c = o4 & 63;
        float acc = wsl[o4];
#pragma unroll 8
        for (int j = 0; j < 64; ++j) acc += Vl[o * 64 + j] * wvl[j * 64 + c];
        ws[OFF_P + (size_t)zb * 4096 + o4] = acc;
    }
    // ph6: cv half (z=0 carries b_ch)
    if (tid < 64) {
        const int o = tid;
        float acc = z ? 0.f : b_ch[o];
        for (int r = 0; r < 64; ++r) acc += wsl[o * 64 + r] * cstz[r];
        ws[OFF_CV2 + (size_t)zb * 64 + o] = acc;
    }
}

// ---------------- K3: logits via MFMA, double-buffered LDS staging -------
__global__ __launch_bounds__(256, 2) void k_logits(const float* __restrict__ x,
        const float* __restrict__ y, const float* __restrict__ w_aw,
        const float* __restrict__ b_aw, float* __restrict__ ws) {
    const int b = blockIdx.y;
    const int bx = blockIdx.x;               // 0..127
    const int tid = threadIdx.x;
    const int wid = tid >> 6, lane = tid & 63;
    const int lr = lane & 15, lg = lane >> 4;

    __shared__ float XT[2][64 * 65], YT[2][64 * 65];   // pad 65, double-buffered
    __shared__ float wsum[4];

    const float* Pbase = ws + OFF_P + (size_t)b * 4096;
    const float* Qbase = ws + OFF_P + (size_t)(4 + b) * 4096;

    bf16x8 AP[4][2], AQ[4][2];               // [o-tile][k-step]
#pragma unroll
    for (int ot = 0; ot < 4; ++ot)
#pragma unroll
        for (int ks = 0; ks < 2; ++ks) {
            const int off = (ot * 16 + lr) * 64 + ks * 32 + lg * 8;
            AP[ot][ks] = ld_cvt(Pbase + off);
            AQ[ot][ks] = ld_cvt(Qbase + off);
        }

    float awr[4][4], cvr[4][4];
#pragma unroll
    for (int ot = 0; ot < 4; ++ot)
#pragma unroll
        for (int r = 0; r < 4; ++r) {
            const int o = ot * 16 + lg * 4 + r;
            awr[ot][r] = w_aw[o];
            cvr[ot][r] = ws[OFF_CV2 + b * 64 + o] + ws[OFF_CV2 + (4 + b) * 64 + o];
        }
    const float baw0 = b_aw[0];

    const float* xb = x + (size_t)b * CC * NN;
    const float* yb = y + (size_t)b * CC * NN;
    const int srow = tid >> 2;               // staging: channel row 0..63
    const int scol = (tid & 3) * 16;         // 16-px slice
    const size_t sbase = (size_t)srow * NN + bx * 512 + scol;
    const int ldso = srow * 65 + scol;

    f32x4 rx0, rx1, rx2, rx3, ry0, ry1, ry2, ry3;
    // prologue: load + write chunk 0 into buf 0
    {
        const float* xs = xb + sbase;
        const float* ys = yb + sbase;
        rx0 = *(const f32x4*)xs;       rx1 = *(const f32x4*)(xs + 4);
        rx2 = *(const f32x4*)(xs + 8); rx3 = *(const f32x4*)(xs + 12);
        ry0 = *(const f32x4*)ys;       ry1 = *(const f32x4*)(ys + 4);
        ry2 = *(const f32x4*)(ys + 8); ry3 = *(const f32x4*)(ys + 12);
        float* xd = &XT[0][ldso];
        float* yd = &YT[0][ldso];
#pragma unroll
        for (int i = 0; i < 4; ++i) {
            xd[i] = rx0[i]; xd[4 + i] = rx1[i]; xd[8 + i] = rx2[i]; xd[12 + i] = rx3[i];
            yd[i] = ry0[i]; yd[4 + i] = ry1[i]; yd[8 + i] = ry2[i]; yd[12 + i] = ry3[i];
        }
    }
    __syncthreads();

    float esum = 0.f;
#pragma unroll 1
    for (int ch = 0; ch < 8; ++ch) {
        const int cur = ch & 1;
        // ---- issue next-chunk global loads (latency hides under compute) --
        if (ch < 7) {
            const float* xs = xb + sbase + (ch + 1) * 64;
            const float* ys = yb + sbase + (ch + 1) * 64;
            rx0 = *(const f32x4*)xs;       rx1 = *(const f32x4*)(xs + 4);
            rx2 = *(const f32x4*)(xs + 8); rx3 = *(const f32x4*)(xs + 12);
            ry0 = *(const f32x4*)ys;       ry1 = *(const f32x4*)(ys + 4);
            ry2 = *(const f32x4*)(ys + 8); ry3 = *(const f32x4*)(ys + 12);
        }
        // ---- compute current chunk from LDS buf `cur` ----
        const int p0 = bx * 512 + ch * 64;
        const int pl = wid * 16 + lr;        // local pixel
        const unsigned int* XU = (const unsigned int*)XT[cur];
        const unsigned int* YU = (const unsigned int*)YT[cur];
        bf16x8 BX[2], BY[2];
#pragma unroll
        for (int ks = 0; ks < 2; ++ks) {
            const int c0 = ks * 32 + lg * 8;
            union { u32x4 u; bf16x8 s; } fx, fy;
#pragma unroll
            for (int q = 0; q < 4; ++q) {
                const unsigned int xa = XU[(c0 + 2 * q) * 65 + pl];
                const unsigned int xbv = XU[(c0 + 2 * q + 1) * 65 + pl];
                fx.u[q] = __builtin_amdgcn_perm(xbv, xa, PSEL);
                const unsigned int ya = YU[(c0 + 2 * q) * 65 + pl];
                const unsigned int ybv = YU[(c0 + 2 * q + 1) * 65 + pl];
                fy.u[q] = __builtin_amdgcn_perm(ybv, ya, PSEL);
            }
            BX[ks] = fx.s; BY[ks] = fy.s;
        }
        f32x4 Cf[4];
#pragma unroll
        for (int ot = 0; ot < 4; ++ot) Cf[ot] = (f32x4){0.f, 0.f, 0.f, 0.f};
#pragma unroll
        for (int ot = 0; ot < 4; ++ot)
#pragma unroll
            for (int ks = 0; ks < 2; ++ks) {
                Cf[ot] = MFMA(AP[ot][ks], BX[ks], Cf[ot]);
                Cf[ot] = MFMA(AQ[ot][ks], BY[ks], Cf[ot]);
            }
        float partial = 0.f;
#pragma unroll
        for (int ot = 0; ot < 4; ++ot)
#pragma unroll
            for (int r = 0; r < 4; ++r)
                partial += awr[ot][r] * fast_tanh(Cf[ot][r] + cvr[ot][r]);
        partial += __shfl_xor(partial, 16);
        partial += __shfl_xor(partial, 32);
        const float e = __expf(partial + baw0);   // no-max softmax: |logit| small
        if (lane < 16)
            ws[OFF_L + (size_t)b * NN + p0 + wid * 16 + lane] = e;
        esum += e * 0.25f;                        // 4 identical copies per pixel
        // ---- write next chunk into the other buffer ----
        if (ch < 7) {
            float* xd = &XT[cur ^ 1][ldso];
            float* yd = &YT[cur ^ 1][ldso];
#pragma unroll
            for (int i = 0; i < 4; ++i) {
                xd[i] = rx0[i]; xd[4 + i] = rx1[i]; xd[8 + i] = rx2[i]; xd[12 + i] = rx3[i];
                yd[i] = ry0[i]; yd[4 + i] = ry1[i]; yd[8 + i] = ry2[i]; yd[12 + i] = ry3[i];
            }
        }
        __syncthreads();                          // write(next) -> read(next)
    }
    // block-deterministic partial sum
#pragma unroll
    for (int d = 1; d < 64; d <<= 1) esum += __shfl_xor(esum, d);
    if (lane == 0) wsum[wid] = esum;
    __syncthreads();
    if (tid == 0)
        ws[OFF_PS + (size_t)b * 128 + bx] = wsum[0] + wsum[1] + wsum[2] + wsum[3];
}

// ---------------- K5: out = in * (1 + e/S), both outputs -----------------
__global__ __launch_bounds__(256) void k_final(const float* __restrict__ x,
        const float* __restrict__ y, const float* __restrict__ ws,
        float* __restrict__ out) {
    const int gid = blockIdx.x * 256 + threadIdx.x;   // 2,097,152
    const int b = gid >> 19;
    // deterministic per-batch sum of 128 block partials (identical in every block)
    const int lane = threadIdx.x & 63;
    const float* ps = ws + OFF_PS + (size_t)b * 128;
    float s = ps[lane] + ps[64 + lane];
#pragma unroll
    for (int d = 1; d < 64; d <<= 1) s += __shfl_xor(s, d);
    const float inv = 1.f / s;

    const int rem = gid & 524287;
    const int c = rem >> 13;
    const int n0 = (rem & 8191) * 8;
    const float* w = ws + OFF_L + (size_t)b * NN + n0;
    const f32x4 w0 = *(const f32x4*)w;
    const f32x4 w1 = *(const f32x4*)(w + 4);
    const size_t idx = ((size_t)(b * 64 + c)) * NN + n0;
    const f32x4 x0 = *(const f32x4*)(x + idx);
    const f32x4 x1 = *(const f32x4*)(x + idx + 4);
    const f32x4 y0 = *(const f32x4*)(y + idx);
    const f32x4 y1 = *(const f32x4*)(y + idx + 4);
    f32x4 o0, o1, o2, o3;
#pragma unroll
    for (int j = 0; j < 4; ++j) {
        const float s0 = 1.f + w0[j] * inv;
        const float s1 = 1.f + w1[j] * inv;
        o0[j] = x0[j] * s0;
        o1[j] = x1[j] * s1;
        o2[j] = y0[j] * s0;
        o3[j] = y1[j] * s1;
    }
    *(f32x4*)(out + idx) = o0;
    *(f32x4*)(out + idx + 4) = o1;
    *(f32x4*)(out + 16777216UL + idx) = o2;
    *(f32x4*)(out + 16777216UL + idx + 4) = o3;
}

extern "C" void kernel_launch(void* const* d_in, const int* in_sizes, int n_in,
                              void* d_out, int out_size, void* d_ws, size_t ws_size,
                              hipStream_t stream) {
    const float* x    = (const float*)d_in[0];
    const float* y    = (const float*)d_in[1];
    const float* wq   = (const float*)d_in[2];
    const float* bq   = (const float*)d_in[3];
    const float* wk   = (const float*)d_in[4];
    const float* bk   = (const float*)d_in[5];
    const float* wv   = (const float*)d_in[6];
    const float* bv   = (const float*)d_in[7];
    const float* temp = (const float*)d_in[8];
    const float* wch  = (const float*)d_in[9];
    const float* bch  = (const float*)d_in[10];
    const float* wyy  = (const float*)d_in[11];
    const float* waw  = (const float*)d_in[12];
    const float* baw  = (const float*)d_in[13];
    float* out = (float*)d_out;
    float* ws = (float*)d_ws;

    hipLaunchKernelGGL(k_gram, dim3(64, 4, 2), dim3(256), 0, stream, x, y, ws);
    hipLaunchKernelGGL(k_reduce, dim3(130), dim3(256), 0, stream, ws);
    hipLaunchKernelGGL(k_uv, dim3(256), dim3(256), 0, stream, wq, wk, ws);
    hipLaunchKernelGGL(k_attn2, dim3(8), dim3(1024), 0, stream,
                       wq, bq, wk, bk, wv, bv, temp, wch, bch, wyy, ws);
    hipLaunchKernelGGL(k_logits, dim3(128, 4), dim3(256), 0, stream, x, y, waw, baw, ws);
    hipLaunchKernelGGL(k_final, dim3(8192), dim3(256), 0, stream, x, y, ws, out);
}